// Round 3
// baseline (351.128 us; speedup 1.0000x reference)
//
#include <hip/hip_runtime.h>

// SelfAttention: x(4,2048,1024) fp32; Linear y = x @ W^T + b for Q,K,V;
// S = QK^T/32; P = softmax(S); O = P V; out = O @ Wo^T + bo.
// bf16 MFMA (16x16x32) m97-style gemm_bt with XOR-swizzled LDS (R2: 0 conflicts).
// R3: (a) fused Q+K projection (N=2048 concat weights), (b) V^T produced
//     directly as gemm_bt(Wv, x) -> no V buffer, no transpose kernel,
//     (c) S stored bf16 (fp32 accum) -> halves S write + softmax read,
//     (d) in-place bf16 softmax with 16B/lane loads.
// Workspace layout (<=105 MB):
//   [0,16)    xb bf16 [8192][1024]  -> later O (attn out, bf16)
//   [16,20)   wqkb bf16 [2048][1024] (wq rows 0-1023, wk rows 1024-2047)
//   [20,22)   wvb bf16 [1024][1024]
//   [22,24)   wob bf16 [1024][1024]
//   [24,56)   QKbuf bf16 [8192][2048] (cols 0-1023 = Q, 1024-2047 = K)
//   [56,72)   VT bf16 [4][1024][2048]
//   [72,104)  S bf16 [4][2048][2048] -> softmax in place -> P
//   [104,+8K) bqk fp32 [2048]

typedef __bf16 bf16x8 __attribute__((ext_vector_type(8)));
typedef float f32x4 __attribute__((ext_vector_type(4)));
typedef unsigned short ushort8 __attribute__((ext_vector_type(8)));

__device__ __forceinline__ unsigned short f32_to_bf16(float f) {
  unsigned int u = __float_as_uint(f);
  u += 0x7fffu + ((u >> 16) & 1u);   // round-to-nearest-even
  return (unsigned short)(u >> 16);
}

__device__ __forceinline__ float bf16_to_f32(unsigned short u) {
  return __uint_as_float((unsigned int)u << 16);
}

__device__ __forceinline__ void load_lds16(const void* g, void* l) {
  __builtin_amdgcn_global_load_lds(
      (const __attribute__((address_space(1))) void*)g,
      (__attribute__((address_space(3))) void*)l, 16, 0, 0);
}

// ------------------------------------------------------------- cast kernels
__global__ __launch_bounds__(256) void cast_f32_bf16(
    const float4* __restrict__ in, ushort4* __restrict__ out, int n4) {
  int i = blockIdx.x * 256 + threadIdx.x;
  if (i < n4) {
    float4 f = in[i];
    ushort4 u;
    u.x = f32_to_bf16(f.x);
    u.y = f32_to_bf16(f.y);
    u.z = f32_to_bf16(f.z);
    u.w = f32_to_bf16(f.w);
    out[i] = u;
  }
}

// all 4 weight matrices in one launch; wq,wk go into concat wqkb
__global__ __launch_bounds__(256) void cast_weights(
    const float4* __restrict__ wq, const float4* __restrict__ wk,
    const float4* __restrict__ wv, const float4* __restrict__ wo,
    ushort4* __restrict__ wqkb, ushort4* __restrict__ wvb,
    ushort4* __restrict__ wob) {
  const int b = blockIdx.x;
  const int seg = b >> 10;                       // 0..3
  const int idx = ((b & 1023) << 8) + threadIdx.x;  // 0..262143 float4s
  const float4* src = seg == 0 ? wq : seg == 1 ? wk : seg == 2 ? wv : wo;
  ushort4* dst = seg == 0 ? wqkb
               : seg == 1 ? (wqkb + 262144)
               : seg == 2 ? wvb : wob;
  float4 f = src[idx];
  ushort4 u;
  u.x = f32_to_bf16(f.x);
  u.y = f32_to_bf16(f.y);
  u.z = f32_to_bf16(f.z);
  u.w = f32_to_bf16(f.w);
  dst[idx] = u;
}

__global__ __launch_bounds__(256) void concat_bias(
    const float* __restrict__ bq, const float* __restrict__ bk,
    float* __restrict__ bqk) {
  int i = blockIdx.x * 256 + threadIdx.x;  // grid 8 -> 2048
  bqk[i] = (i < 1024) ? bq[i] : bk[i - 1024];
}

// ------------------------------------------------------------ gemm (B^T form)
// C[b][M][N] = alpha * A[b][M][K] * B[b][N][K]^T + bias
// bias_mode: 0 none, 1 per-col (bias[N]), 2 per-row (bias[M]).
// Tile 128x128, BK=64, 4 waves 2x2, 4x4 16x16x32 MFMA acc per wave.
// LDS: physical 16B chunk p of row r holds logical chunk p^(r&7) (no conflicts).
__global__ __launch_bounds__(256) void gemm_bt(
    const unsigned short* __restrict__ A, const unsigned short* __restrict__ B,
    void* __restrict__ C, const float* __restrict__ bias,
    int M, int N, int K, int ldA, int ldB, int ldC,
    float alpha, int out_bf16, int bias_mode,
    long long sA, long long sB, long long sC) {
  __shared__ unsigned short As[128 * 64];
  __shared__ unsigned short Bs[128 * 64];

  const int bz = blockIdx.z;
  A += (long long)bz * sA;
  B += (long long)bz * sB;

  const int bm = blockIdx.y, bn = blockIdx.x;
  const int tid = threadIdx.x;
  const int lane = tid & 63, wave = tid >> 6;
  const int wr = wave >> 1, wc = wave & 1;
  const int l16 = lane & 15, quad = lane >> 4;

  f32x4 acc[4][4] = {};

  // staging: thread t covers row (t>>3)+32r; LDS physical chunk (t&7) gets
  // logical chunk (t&7)^(row&7).
  const int srow = tid >> 3;
  const int xr = srow & 7;
  const int scol = ((tid & 7) ^ xr) * 8;
  const unsigned short* gA = A + (long long)(bm * 128 + srow) * ldA + scol;
  const unsigned short* gB = B + (long long)(bn * 128 + srow) * ldB + scol;
  char* ldsA = (char*)As + wave * 1024;  // wave-uniform base; HW adds lane*16
  char* ldsB = (char*)Bs + wave * 1024;

  for (int k0 = 0; k0 < K; k0 += 64) {
#pragma unroll
    for (int r = 0; r < 4; r++)
      load_lds16(gA + k0 + (long long)r * 32 * ldA, ldsA + r * 4096);
#pragma unroll
    for (int r = 0; r < 4; r++)
      load_lds16(gB + k0 + (long long)r * 32 * ldB, ldsB + r * 4096);
    __syncthreads();  // drains vmcnt: LDS tiles ready

    const int swz = l16 & 7;
#pragma unroll
    for (int kk = 0; kk < 64; kk += 32) {
      bf16x8 af[4], bf[4];
      const int lc = (kk >> 3) + quad;   // logical chunk 0..7
      const int pco = (lc ^ swz) * 8;    // physical chunk offset, elems
#pragma unroll
      for (int mi = 0; mi < 4; mi++)
        af[mi] = *(const bf16x8*)(As + (wr * 64 + mi * 16 + l16) * 64 + pco);
#pragma unroll
      for (int ni = 0; ni < 4; ni++)
        bf[ni] = *(const bf16x8*)(Bs + (wc * 64 + ni * 16 + l16) * 64 + pco);
#pragma unroll
      for (int mi = 0; mi < 4; mi++)
#pragma unroll
        for (int ni = 0; ni < 4; ni++)
          acc[mi][ni] = __builtin_amdgcn_mfma_f32_16x16x32_bf16(
              af[mi], bf[ni], acc[mi][ni], 0, 0, 0);
    }
    __syncthreads();  // protect LDS before next stage overwrites
  }

  // epilogue: D element (row = quad*4+reg, col = l16) per 16x16 tile
  const int orow0 = bm * 128 + wr * 64 + quad * 4;
  const int ocol0 = bn * 128 + wc * 64 + l16;
  if (out_bf16) {
    unsigned short* Cp = (unsigned short*)C + (long long)bz * sC;
#pragma unroll
    for (int mi = 0; mi < 4; mi++)
#pragma unroll
      for (int ni = 0; ni < 4; ni++) {
        const int col = ocol0 + ni * 16;
        const float cb = (bias_mode == 1) ? bias[col] : 0.f;
#pragma unroll
        for (int r = 0; r < 4; r++) {
          const int row = orow0 + mi * 16 + r;
          const float bv = (bias_mode == 2) ? bias[row] : cb;
          const float o = acc[mi][ni][r] * alpha + bv;
          Cp[(long long)row * ldC + col] = f32_to_bf16(o);
        }
      }
  } else {
    float* Cp = (float*)C + (long long)bz * sC;
#pragma unroll
    for (int mi = 0; mi < 4; mi++)
#pragma unroll
      for (int ni = 0; ni < 4; ni++) {
        const int col = ocol0 + ni * 16;
        const float cb = (bias_mode == 1) ? bias[col] : 0.f;
#pragma unroll
        for (int r = 0; r < 4; r++) {
          const int row = orow0 + mi * 16 + r;
          const float bv = (bias_mode == 2) ? bias[row] : cb;
          const float o = acc[mi][ni][r] * alpha + bv;
          Cp[(long long)row * ldC + col] = o;
        }
      }
  }
}

// ------------------------------------------------------- row softmax, bf16
// S: [8192][2048] bf16, in place. One block (256 thr) per row; 8 elems/thread.
__global__ __launch_bounds__(256) void softmax_rows_bf16(
    unsigned short* __restrict__ S) {
  const long long row = blockIdx.x;
  unsigned short* s = S + row * 2048;
  const int t = threadIdx.x;
  ushort8 u = *(const ushort8*)(s + t * 8);
  float v[8];
  float mx = -3.4e38f;
#pragma unroll
  for (int i = 0; i < 8; i++) {
    v[i] = bf16_to_f32(u[i]);
    mx = fmaxf(mx, v[i]);
  }
#pragma unroll
  for (int o = 32; o >= 1; o >>= 1) mx = fmaxf(mx, __shfl_xor(mx, o));
  __shared__ float red[4], red2[4];
  if ((t & 63) == 0) red[t >> 6] = mx;
  __syncthreads();
  mx = fmaxf(fmaxf(red[0], red[1]), fmaxf(red[2], red[3]));
  float sum = 0.f;
#pragma unroll
  for (int i = 0; i < 8; i++) {
    v[i] = __expf(v[i] - mx);
    sum += v[i];
  }
#pragma unroll
  for (int o = 32; o >= 1; o >>= 1) sum += __shfl_xor(sum, o);
  if ((t & 63) == 0) red2[t >> 6] = sum;
  __syncthreads();
  sum = red2[0] + red2[1] + red2[2] + red2[3];
  const float inv = 1.0f / sum;
  ushort8 w;
#pragma unroll
  for (int i = 0; i < 8; i++) w[i] = f32_to_bf16(v[i] * inv);
  *(ushort8*)(s + t * 8) = w;
}

// ----------------------------------------------------------------- launcher
extern "C" void kernel_launch(void* const* d_in, const int* in_sizes, int n_in,
                              void* d_out, int out_size, void* d_ws,
                              size_t ws_size, hipStream_t stream) {
  const float* x = (const float*)d_in[0];
  const float* wq = (const float*)d_in[1];
  const float* bq = (const float*)d_in[2];
  const float* wk = (const float*)d_in[3];
  const float* bk = (const float*)d_in[4];
  const float* wv = (const float*)d_in[5];
  const float* bv = (const float*)d_in[6];
  const float* wo = (const float*)d_in[7];
  const float* bo = (const float*)d_in[8];
  float* out = (float*)d_out;
  char* ws = (char*)d_ws;
  const size_t MB = 1ull << 20;

  unsigned short* xb   = (unsigned short*)(ws + 0);        // 16MB, later O
  unsigned short* wqkb = (unsigned short*)(ws + 16 * MB);  // 4MB concat
  unsigned short* wvb  = (unsigned short*)(ws + 20 * MB);  // 2MB
  unsigned short* wob  = (unsigned short*)(ws + 22 * MB);  // 2MB
  unsigned short* QK   = (unsigned short*)(ws + 24 * MB);  // 32MB [8192][2048]
  unsigned short* VT   = (unsigned short*)(ws + 56 * MB);  // 16MB [4][1024][2048]
  unsigned short* S    = (unsigned short*)(ws + 72 * MB);  // 32MB, softmax in place
  float*          bqk  = (float*)(ws + 104 * MB);          // 8KB
  unsigned short* O    = xb;                               // 16MB over x

  // 1) casts
  cast_f32_bf16<<<dim3(8192), dim3(256), 0, stream>>>((const float4*)x,
                                                      (ushort4*)xb, 2097152);
  cast_weights<<<dim3(4096), dim3(256), 0, stream>>>(
      (const float4*)wq, (const float4*)wk, (const float4*)wv,
      (const float4*)wo, (ushort4*)wqkb, (ushort4*)wvb, (ushort4*)wob);
  concat_bias<<<dim3(8), dim3(256), 0, stream>>>(bq, bk, bqk);

  // 2) fused Q+K projection: QK[8192][2048] = xb @ wqkb^T + bqk (bf16)
  gemm_bt<<<dim3(16, 64, 1), dim3(256), 0, stream>>>(
      xb, wqkb, QK, bqk, 8192, 2048, 1024, 1024, 1024, 2048, 1.f, 1, 1, 0, 0,
      0);

  // 3) VT[b][d][s] = sum_k wv[d][k] x[b][s][k] + bv[d]  (per-row bias)
  gemm_bt<<<dim3(16, 8, 4), dim3(256), 0, stream>>>(
      wvb, xb, VT, bv, 1024, 2048, 1024, 1024, 1024, 2048, 1.f, 1, 2, 0,
      2048ll * 1024, 1024ll * 2048);

  // 4) S = Q K^T / 32 (bf16 out, fp32 accum), batched over 4
  gemm_bt<<<dim3(16, 16, 4), dim3(256), 0, stream>>>(
      QK, QK + 1024, S, nullptr, 2048, 2048, 1024, 2048, 2048, 2048, 0.03125f,
      1, 0, 2048ll * 2048, 2048ll * 2048, 2048ll * 2048);

  // 5) P = softmax rows of S, in place
  softmax_rows_bf16<<<dim3(8192), dim3(256), 0, stream>>>(S);

  // 6) O = P @ V (B = VT in B^T form), bf16, over xb
  gemm_bt<<<dim3(8, 16, 4), dim3(256), 0, stream>>>(
      S, VT, O, nullptr, 2048, 1024, 2048, 2048, 2048, 1024, 1.f, 1, 0,
      2048ll * 2048, 1024ll * 2048, 2048ll * 1024);

  // 7) out = O @ Wo^T + bo, fp32 to d_out
  gemm_bt<<<dim3(8, 64, 1), dim3(256), 0, stream>>>(
      O, wob, out, bo, 8192, 1024, 1024, 1024, 1024, 1024, 1.f, 0, 1, 0, 0, 0);
}